// Round 11
// baseline (2146.351 us; speedup 1.0000x reference)
//
#include <hip/hip_runtime.h>

typedef _Float16 half8 __attribute__((ext_vector_type(8)));
typedef float float4v __attribute__((ext_vector_type(4)));
typedef unsigned long long u64;

#define TSEQ  1024
#define BATCH 128
#define HID   512
#define DIN   128

// LDS: double-buffered h tile. Row stride 264 b32-words (528 halves) so the
// MFMA ds_read_b128 pattern lands 2-way max (free).
#define HW_STRIDE 264                        // b32 words per row
#define HBUF_WORDS (8 * HW_STRIDE)           // 2112 words per buffer
#define GOFF (2 * HBUF_WORDS * 4)            // 16896 B
#define PUB_OFF (GOFF + 4 * 8 * 32 * 4)      // gate scratch ends here
#define LDS_BYTES (PUB_OFF + 512)            // + 8x32 fp16 publish tile

// d_ws layout
#define WS_H16_OFF  0                                // [2][128][512] fp16 = 256 KiB
#define WS_BAR_OFF  (2 * BATCH * HID * 2)            // 262144
#define WS_XALL_OFF (1u << 20)                       // 1 MiB
#define WS_NEED     ((size_t)WS_XALL_OFF + (size_t)TSEQ * BATCH * DIN * 2)

__device__ inline half8 cvt8(float4v a, float4v b) {
    half8 r;
    r[0] = (_Float16)a[0]; r[1] = (_Float16)a[1];
    r[2] = (_Float16)a[2]; r[3] = (_Float16)a[3];
    r[4] = (_Float16)b[0]; r[5] = (_Float16)b[1];
    r[6] = (_Float16)b[2]; r[7] = (_Float16)b[3];
    return r;
}

// branch-free sigmoid / tanh on v_exp_f32 + v_rcp_f32
__device__ inline float sigm(float x) {
    return __builtin_amdgcn_rcpf(1.0f + __builtin_amdgcn_exp2f(-1.44269504f * x));
}
__device__ inline float tanh_fast(float x) { return 2.0f * sigm(2.0f * x) - 1.0f; }

// 16 teams x 16 CUs. Team owns rows [8t,8t+8); CU p owns units [32p,32p+32);
// wave w owns units [..+8w..). Weights VGPR-resident fp16 for the whole run.
// h handoff: RAW fp16, double-buffered, mantissa LSB = phase ((t>>1)&1)^1 —
// each 2-byte value self-describes freshness; relaxed AGENT atomics.
// [Session ledger: R1/R2/R4 scope variants starve/regress — agent scope
//  everywhere. R5 dual-team loses 2x CUs. R6 early-issue samples too early.
//  R7 row-coalescing neutral. R8 register-direct h amplifies requests 8x.
//  R9 multi-sample retry neutral. R10 WIN (-130us): single-store-per-sector
//  publish — WRITE_SIZE 171->104MB confirms the invalidate/refetch model.]
// R11: SPLIT-TILE POLL/MFMA PIPELINE. u64 poll group j covers kt in
// [4j,4j+4) (j = kt>>2). Step becomes: finish j0+j1 -> barrier A ->
// speculatively ISSUE retries for pending j2/j3 (no wait) -> h-MFMA kt0..7
// (covers the retry RT) -> finish j2+j3 -> barrier B -> h-MFMA kt8..15.
// Hides ~1 retry RT (~850cyc IF service) on miss steps for +1 barrier.
// Poison 0xAAAA has LSB 0 != first expected phase 1 -> no init required.
template <bool XA>
__global__ __launch_bounds__(256, 1)
void lstm_persistent(const int* __restrict__ ids,
                     const int* __restrict__ seq_len,
                     const float* __restrict__ emb,
                     const float* __restrict__ w_ih,
                     const float* __restrict__ w_hh,
                     const float* __restrict__ b_ih,
                     const float* __restrict__ b_hh,
                     float* __restrict__ out,
                     _Float16* __restrict__ h16,      // [2][128][512] fp16
                     _Float16* __restrict__ x_all,    // [T][128][128] fp16
                     int* __restrict__ bar)
{
    __shared__ __align__(16) char smem[LDS_BYTES];
    unsigned* hsu = (unsigned*)smem;
    _Float16* hsh = (_Float16*)smem;
    float*    gs  = (float*)(smem + GOFF);
    unsigned short* pub = (unsigned short*)(smem + PUB_OFF);

    const int tid  = threadIdx.x;
    const int lane = tid & 63;
    const int wv   = tid >> 6;
    const int team = blockIdx.x & 15;
    const int p    = blockIdx.x >> 4;
    const int rowbase   = team * 8;
    const int unit_base = p * 32 + wv * 8;

    const int col  = lane & 15;   // MFMA n / C col
    const int kq   = lane >> 4;   // MFMA k-quad
    const int arow = lane & 7;    // A row (rows 8..15 duplicate 0..7)
    const int my_row  = lane >> 3;
    const int my_unit = unit_base + (lane & 7);

    if (XA) {
        // ---- phase 0: gather x_all[t][b][:] = fp16(emb[ids[t][b]][:]) ----
        for (int pair = blockIdx.x * 256 + tid; pair < TSEQ * BATCH;
             pair += 256 * 256) {
            const float* src = emb + (size_t)ids[pair] * DIN;   // pair = t*128+b
            _Float16* dst = x_all + (size_t)pair * DIN;
#pragma unroll
            for (int k = 0; k < 16; ++k) {
                float4v a = *(const float4v*)(src + k * 8);
                float4v c = *(const float4v*)(src + k * 8 + 4);
                *(half8*)(dst + k * 8) = cvt8(a, c);
            }
        }
        // ---- one-time grid barrier (full release/acquire, only here) ----
        __threadfence();
        __syncthreads();
        if (tid == 0) {
            __hip_atomic_fetch_add(bar, 1, __ATOMIC_RELEASE,
                                   __HIP_MEMORY_SCOPE_AGENT);
            int g = 0;
            while (__hip_atomic_load(bar, __ATOMIC_ACQUIRE,
                                     __HIP_MEMORY_SCOPE_AGENT) < 256
                   && ++g < (1 << 26)) { }
        }
        __syncthreads();
        __threadfence();
    }

    int tmax = 0, my_tstar = 0;
    for (int r = 0; r < 8; ++r) {
        int s  = seq_len[rowbase + r];
        int ts = (s > 0) ? (s - 1) : 0;
        if (r == my_row) my_tstar = ts;
        tmax = (ts > tmax) ? ts : tmax;
    }

    // ---- weight fragments -> VGPRs (fp32 -> fp16), once ----
    const int wrow0 = (col & 3) * HID + unit_base + (col >> 2);
    const int wrow1 = (col & 3) * HID + unit_base + 4 + (col >> 2);
    const float bias0 = b_ih[wrow0] + b_hh[wrow0];
    const float bias1 = b_ih[wrow1] + b_hh[wrow1];

    half8 whhf0[16], whhf1[16];
#pragma unroll
    for (int kt = 0; kt < 16; ++kt) {
        const float* s0 = w_hh + (size_t)wrow0 * HID + kt * 32 + kq * 8;
        const float* s1 = w_hh + (size_t)wrow1 * HID + kt * 32 + kq * 8;
        whhf0[kt] = cvt8(*(const float4v*)s0, *(const float4v*)(s0 + 4));
        whhf1[kt] = cvt8(*(const float4v*)s1, *(const float4v*)(s1 + 4));
    }
    half8 wihf0[4], wihf1[4];
#pragma unroll
    for (int kt = 0; kt < 4; ++kt) {
        const float* s0 = w_ih + (size_t)wrow0 * DIN + kt * 32 + kq * 8;
        const float* s1 = w_ih + (size_t)wrow1 * DIN + kt * 32 + kq * 8;
        wihf0[kt] = cvt8(*(const float4v*)s0, *(const float4v*)(s0 + 4));
        wihf1[kt] = cvt8(*(const float4v*)s1, *(const float4v*)(s1 + 4));
    }

    float c_state = 0.0f;
    const int crow = tid >> 5;    // poll/staging: row 0..7, 32 threads/row
    const int coff = tid & 31;    // thread polls u64s {coff + 32j}, j=0..3

    // ---- x fragment pipeline ----
    half8 xf[4], xn[4];
    if (XA) {
        const _Float16* x0 = x_all + ((size_t)0 * BATCH + rowbase + arow) * DIN;
        const int t1 = (tmax > 0) ? 1 : 0;
        const _Float16* x1 = x_all + ((size_t)t1 * BATCH + rowbase + arow) * DIN;
#pragma unroll
        for (int kt = 0; kt < 4; ++kt) {
            xf[kt] = *(const half8*)(x0 + kt * 32 + kq * 8);
            xn[kt] = *(const half8*)(x1 + kt * 32 + kq * 8);
        }
    } else {
        const int id0 = ids[rowbase + arow];
        const float* xrow = emb + (size_t)id0 * DIN;
#pragma unroll
        for (int kt = 0; kt < 4; ++kt) {
            const float* s = xrow + kt * 32 + kq * 8;
            xf[kt] = cvt8(*(const float4v*)s, *(const float4v*)(s + 4));
        }
    }

    // ---- acc(0) = bias + x(0) @ Wih, spread over 8 chains (a..d x 2) ----
    float4v a0 = {bias0, bias0, bias0, bias0}, b0 = {0,0,0,0}, c0 = {0,0,0,0}, d0 = {0,0,0,0};
    float4v a1 = {bias1, bias1, bias1, bias1}, b1 = {0,0,0,0}, c1 = {0,0,0,0}, d1 = {0,0,0,0};
    a0 = __builtin_amdgcn_mfma_f32_16x16x32_f16(xf[0], wihf0[0], a0, 0, 0, 0);
    b0 = __builtin_amdgcn_mfma_f32_16x16x32_f16(xf[1], wihf0[1], b0, 0, 0, 0);
    c0 = __builtin_amdgcn_mfma_f32_16x16x32_f16(xf[2], wihf0[2], c0, 0, 0, 0);
    d0 = __builtin_amdgcn_mfma_f32_16x16x32_f16(xf[3], wihf0[3], d0, 0, 0, 0);
    a1 = __builtin_amdgcn_mfma_f32_16x16x32_f16(xf[0], wihf1[0], a1, 0, 0, 0);
    b1 = __builtin_amdgcn_mfma_f32_16x16x32_f16(xf[1], wihf1[1], b1, 0, 0, 0);
    c1 = __builtin_amdgcn_mfma_f32_16x16x32_f16(xf[2], wihf1[2], c1, 0, 0, 0);
    d1 = __builtin_amdgcn_mfma_f32_16x16x32_f16(xf[3], wihf1[3], d1, 0, 0, 0);

    const u64 LSBM = 0x0001000100010001ull;

    for (int t = 0; t <= tmax; ++t) {
        const int bs = t & 1;    // LDS h-tile buffer for this step
        int id_next = 0;
        if (!XA) {
            const int tn = (t < tmax) ? (t + 1) : t;
            id_next = ids[tn * BATCH + rowbase + arow];
        }

        const u64* rowp = (const u64*)(h16
            + (size_t)((t + 1) & 1) * BATCH * HID + (rowbase + crow) * HID);
        const u64 want = ((((t - 1) >> 1) & 1) ^ 1) ? LSBM : 0ull;
        unsigned* dstw = hsu + bs * HBUF_WORDS + crow * HW_STRIDE + 2 * coff;
        unsigned pending = 0;
        u64 vB[2];

        if (t > 0) {
            // ---- round-0 poll: all 4 word groups ----
            pending = 0xF;
            u64 v[4];
#pragma unroll
            for (int j = 0; j < 4; ++j)
                v[j] = __hip_atomic_load(rowp + coff + 32 * j,
                                         __ATOMIC_RELAXED, __HIP_MEMORY_SCOPE_AGENT);
#pragma unroll
            for (int j = 0; j < 4; ++j) {
                if (((v[j] ^ want) & LSBM) == 0) {
                    *(u64*)(dstw + 64 * j) = v[j];
                    pending &= ~(1u << j);
                }
            }
            // ---- finish group A (j0,j1 -> kt 0..7) ----
            int round = 0, guard = 0;
            while (pending & 0x3u) {
#pragma unroll
                for (int j = 0; j < 2; ++j) {
                    if (pending & (1u << j)) {
                        u64 x = __hip_atomic_load(rowp + coff + 32 * j,
                                                  __ATOMIC_RELAXED,
                                                  __HIP_MEMORY_SCOPE_AGENT);
                        if (((x ^ want) & LSBM) == 0) {
                            *(u64*)(dstw + 64 * j) = x;
                            pending &= ~(1u << j);
                        }
                    }
                }
                if (!(pending & 0x3u)) break;
                if (++round >= 3) __builtin_amdgcn_s_sleep(1);
                if (++guard > (1 << 20)) break;   // anti-hang safety valve
            }
        }
        __syncthreads();   // barrier A: rows for kt 0..7 staged

        float4v xraw[8];
        if (!XA) {
            // fallback: issue emb(t+1) raw loads here (h-MFMA shadow)
            const float* xrow = emb + (size_t)id_next * DIN;
#pragma unroll
            for (int kt = 0; kt < 4; ++kt) {
                xraw[2 * kt]     = *(const float4v*)(xrow + kt * 32 + kq * 8);
                xraw[2 * kt + 1] = *(const float4v*)(xrow + kt * 32 + kq * 8 + 4);
            }
        }

        // ---- speculative retry ISSUE for group B (checked after MFMA A) ----
        if (t > 0 && (pending & 0x4u))
            vB[0] = __hip_atomic_load(rowp + coff + 64,
                                      __ATOMIC_RELAXED, __HIP_MEMORY_SCOPE_AGENT);
        if (t > 0 && (pending & 0x8u))
            vB[1] = __hip_atomic_load(rowp + coff + 96,
                                      __ATOMIC_RELAXED, __HIP_MEMORY_SCOPE_AGENT);

        if (t > 0) {
            // ---- h MFMA group A: kt 0..7 (covers group-B retry RT) ----
            const _Float16* hb = hsh + bs * HBUF_WORDS * 2;
#pragma unroll
            for (int kt = 0; kt < 8; ++kt) {
                half8 af = *(const half8*)(hb + arow * (HW_STRIDE * 2) + kt * 32 + kq * 8);
                switch (kt & 3) {
                case 0:
                    a0 = __builtin_amdgcn_mfma_f32_16x16x32_f16(af, whhf0[kt], a0, 0, 0, 0);
                    a1 = __builtin_amdgcn_mfma_f32_16x16x32_f16(af, whhf1[kt], a1, 0, 0, 0);
                    break;
                case 1:
                    b0 = __builtin_amdgcn_mfma_f32_16x16x32_f16(af, whhf0[kt], b0, 0, 0, 0);
                    b1 = __builtin_amdgcn_mfma_f32_16x16x32_f16(af, whhf1[kt], b1, 0, 0, 0);
                    break;
                case 2:
                    c0 = __builtin_amdgcn_mfma_f32_16x16x32_f16(af, whhf0[kt], c0, 0, 0, 0);
                    c1 = __builtin_amdgcn_mfma_f32_16x16x32_f16(af, whhf1[kt], c1, 0, 0, 0);
                    break;
                default:
                    d0 = __builtin_amdgcn_mfma_f32_16x16x32_f16(af, whhf0[kt], d0, 0, 0, 0);
                    d1 = __builtin_amdgcn_mfma_f32_16x16x32_f16(af, whhf1[kt], d1, 0, 0, 0);
                }
            }
            // ---- finish group B (j2,j3 -> kt 8..15) ----
            if (pending & 0xCu) {
#pragma unroll
                for (int j = 2; j < 4; ++j) {
                    if (pending & (1u << j)) {
                        const u64 x = vB[j - 2];
                        if (((x ^ want) & LSBM) == 0) {
                            *(u64*)(dstw + 64 * j) = x;
                            pending &= ~(1u << j);
                        }
                    }
                }
                int round = 0, guard = 0;
                while (pending & 0xCu) {
#pragma unroll
                    for (int j = 2; j < 4; ++j) {
                        if (pending & (1u << j)) {
                            u64 x = __hip_atomic_load(rowp + coff + 32 * j,
                                                      __ATOMIC_RELAXED,
                                                      __HIP_MEMORY_SCOPE_AGENT);
                            if (((x ^ want) & LSBM) == 0) {
                                *(u64*)(dstw + 64 * j) = x;
                                pending &= ~(1u << j);
                            }
                        }
                    }
                    if (!(pending & 0xCu)) break;
                    if (++round >= 3) __builtin_amdgcn_s_sleep(1);
                    if (++guard > (1 << 20)) break;
                }
            }
        }
        __syncthreads();   // barrier B: rows for kt 8..15 staged

        if (t > 0) {
            // ---- h MFMA group B: kt 8..15 ----
            const _Float16* hb = hsh + bs * HBUF_WORDS * 2;
#pragma unroll
            for (int kt = 8; kt < 16; ++kt) {
                half8 af = *(const half8*)(hb + arow * (HW_STRIDE * 2) + kt * 32 + kq * 8);
                switch (kt & 3) {
                case 0:
                    a0 = __builtin_amdgcn_mfma_f32_16x16x32_f16(af, whhf0[kt], a0, 0, 0, 0);
                    a1 = __builtin_amdgcn_mfma_f32_16x16x32_f16(af, whhf1[kt], a1, 0, 0, 0);
                    break;
                case 1:
                    b0 = __builtin_amdgcn_mfma_f32_16x16x32_f16(af, whhf0[kt], b0, 0, 0, 0);
                    b1 = __builtin_amdgcn_mfma_f32_16x16x32_f16(af, whhf1[kt], b1, 0, 0, 0);
                    break;
                case 2:
                    c0 = __builtin_amdgcn_mfma_f32_16x16x32_f16(af, whhf0[kt], c0, 0, 0, 0);
                    c1 = __builtin_amdgcn_mfma_f32_16x16x32_f16(af, whhf1[kt], c1, 0, 0, 0);
                    break;
                default:
                    d0 = __builtin_amdgcn_mfma_f32_16x16x32_f16(af, whhf0[kt], d0, 0, 0, 0);
                    d1 = __builtin_amdgcn_mfma_f32_16x16x32_f16(af, whhf1[kt], d1, 0, 0, 0);
                }
            }
        }
        const float4v g0 = (a0 + b0) + (c0 + d0);
        const float4v g1 = (a1 + b1) + (c1 + d1);

        // ---- regroup i,f,g,o per (row,unit) via per-wave LDS scratch ----
        float* gw = gs + wv * 256;
        if (lane < 32) {
            const int grow = (lane >> 4) * 4;
#pragma unroll
            for (int r = 0; r < 4; ++r) {
                gw[(grow + r) * 32 + col]      = g0[r];
                gw[(grow + r) * 32 + 16 + col] = g1[r];
            }
        }
        const float4v g4 = *(const float4v*)(gw + my_row * 32 + (lane & 7) * 4);

        const float i_s = sigm(g4[0]);
        const float f_s = sigm(g4[1]);
        const float g_t = tanh_fast(g4[2]);
        const float o_s = sigm(g4[3]);
        c_state = f_s * c_state + i_s * g_t;
        const float hn = o_s * tanh_fast(c_state);

        if (t == my_tstar)
            out[(rowbase + my_row) * HID + my_unit] = c_state;

        // ---- publish h, SINGLE STORE PER SECTOR (R10): stage tagged fp16 in
        //      the block's LDS pub tile, barrier, then wave 0 stores 64
        //      coalesced u64s (each 64B sector written completely by 8
        //      adjacent lanes in one wave-instruction) ----
        {
            const unsigned pub_phase = (((unsigned)t >> 1) & 1u) ^ 1u;
            unsigned short hb16 = __builtin_bit_cast(unsigned short, (_Float16)hn);
            hb16 = (unsigned short)((hb16 & 0xFFFEu) | pub_phase);
            pub[my_row * 32 + wv * 8 + (lane & 7)] = hb16;
        }
        __syncthreads();   // publish-staging barrier
        if (tid < 64) {
            const int r = tid >> 3, seg = tid & 7;
            const u64 pk = *(const u64*)(pub + r * 32 + seg * 4);
            __hip_atomic_store((u64*)((unsigned short*)h16
                                   + (size_t)(t & 1) * BATCH * HID
                                   + (rowbase + r) * HID + p * 32) + seg,
                               pk, __ATOMIC_RELAXED, __HIP_MEMORY_SCOPE_AGENT);
        }

        // ---- filler between publish and next poll: x pipeline + x-MFMA(t+1)
        //      then a tuned s_sleep so poll round-0 samples past producer
        //      visibility ----
        if (XA) {
#pragma unroll
            for (int kt = 0; kt < 4; ++kt) xf[kt] = xn[kt];
            const int t2 = (t + 2 <= tmax) ? (t + 2) : tmax;
            const _Float16* xs2 = x_all + ((size_t)t2 * BATCH + rowbase + arow) * DIN;
#pragma unroll
            for (int kt = 0; kt < 4; ++kt)
                xn[kt] = *(const half8*)(xs2 + kt * 32 + kq * 8);
        } else {
#pragma unroll
            for (int kt = 0; kt < 4; ++kt)
                xf[kt] = cvt8(xraw[2 * kt], xraw[2 * kt + 1]);
        }

        a0 = (float4v){bias0, bias0, bias0, bias0}; b0 = (float4v){0,0,0,0};
        c0 = (float4v){0,0,0,0};                    d0 = (float4v){0,0,0,0};
        a1 = (float4v){bias1, bias1, bias1, bias1}; b1 = (float4v){0,0,0,0};
        c1 = (float4v){0,0,0,0};                    d1 = (float4v){0,0,0,0};
        a0 = __builtin_amdgcn_mfma_f32_16x16x32_f16(xf[0], wihf0[0], a0, 0, 0, 0);
        b0 = __builtin_amdgcn_mfma_f32_16x16x32_f16(xf[1], wihf0[1], b0, 0, 0, 0);
        c0 = __builtin_amdgcn_mfma_f32_16x16x32_f16(xf[2], wihf0[2], c0, 0, 0, 0);
        d0 = __builtin_amdgcn_mfma_f32_16x16x32_f16(xf[3], wihf0[3], d0, 0, 0, 0);
        a1 = __builtin_amdgcn_mfma_f32_16x16x32_f16(xf[0], wihf1[0], a1, 0, 0, 0);
        b1 = __builtin_amdgcn_mfma_f32_16x16x32_f16(xf[1], wihf1[1], b1, 0, 0, 0);
        c1 = __builtin_amdgcn_mfma_f32_16x16x32_f16(xf[2], wihf1[2], c1, 0, 0, 0);
        d1 = __builtin_amdgcn_mfma_f32_16x16x32_f16(xf[3], wihf1[3], d1, 0, 0, 0);

        // tuned pre-poll delay: ~384 cyc (producer store->IF visibility + skew)
        __builtin_amdgcn_s_sleep(6);
    }
}

extern "C" void kernel_launch(void* const* d_in, const int* in_sizes, int n_in,
                              void* d_out, int out_size, void* d_ws, size_t ws_size,
                              hipStream_t stream)
{
    const int*   ids  = (const int*)d_in[0];
    const int*   slen = (const int*)d_in[1];
    const float* emb  = (const float*)d_in[2];
    const float* wih  = (const float*)d_in[3];
    const float* whh  = (const float*)d_in[4];
    const float* bih  = (const float*)d_in[5];
    const float* bhh  = (const float*)d_in[6];
    float* out = (float*)d_out;

    _Float16* h16   = (_Float16*)((char*)d_ws + WS_H16_OFF);
    int*      bar   = (int*)((char*)d_ws + WS_BAR_OFF);
    _Float16* x_all = (_Float16*)((char*)d_ws + WS_XALL_OFF);

    if (ws_size >= WS_NEED) {
        hipMemsetAsync(bar, 0, sizeof(int), stream);
        hipLaunchKernelGGL((lstm_persistent<true>), dim3(256), dim3(256), 0, stream,
                           ids, slen, emb, wih, whh, bih, bhh, out,
                           h16, x_all, bar);
    } else {
        hipLaunchKernelGGL((lstm_persistent<false>), dim3(256), dim3(256), 0, stream,
                           ids, slen, emb, wih, whh, bih, bhh, out,
                           h16, x_all, bar);
    }
}

// Round 12
// 1926.116 us; speedup vs baseline: 1.1143x; 1.1143x over previous
//
#include <hip/hip_runtime.h>

typedef _Float16 half8 __attribute__((ext_vector_type(8)));
typedef float float4v __attribute__((ext_vector_type(4)));
typedef unsigned long long u64;

#define TSEQ  1024
#define BATCH 128
#define HID   512
#define DIN   128

// LDS: double-buffered h tile. Row stride 264 b32-words (528 halves) so the
// MFMA ds_read_b128 pattern lands 2-way max (free).
#define HW_STRIDE 264                        // b32 words per row
#define HBUF_WORDS (8 * HW_STRIDE)           // 2112 words per buffer
#define GOFF (2 * HBUF_WORDS * 4)            // 16896 B
#define PUB_OFF (GOFF + 4 * 8 * 32 * 4)      // gate scratch ends here
#define LDS_BYTES (PUB_OFF + 512)            // + 8x32 fp16 publish tile

// d_ws layout
#define WS_H16_OFF  0                                // [2][128][512] fp16 = 256 KiB
#define WS_BAR_OFF  (2 * BATCH * HID * 2)            // 262144
#define WS_XALL_OFF (1u << 20)                       // 1 MiB
#define WS_NEED     ((size_t)WS_XALL_OFF + (size_t)TSEQ * BATCH * DIN * 2)

__device__ inline half8 cvt8(float4v a, float4v b) {
    half8 r;
    r[0] = (_Float16)a[0]; r[1] = (_Float16)a[1];
    r[2] = (_Float16)a[2]; r[3] = (_Float16)a[3];
    r[4] = (_Float16)b[0]; r[5] = (_Float16)b[1];
    r[6] = (_Float16)b[2]; r[7] = (_Float16)b[3];
    return r;
}

// branch-free sigmoid / tanh on v_exp_f32 + v_rcp_f32
__device__ inline float sigm(float x) {
    return __builtin_amdgcn_rcpf(1.0f + __builtin_amdgcn_exp2f(-1.44269504f * x));
}
__device__ inline float tanh_fast(float x) { return 2.0f * sigm(2.0f * x) - 1.0f; }

// 16 teams x 16 CUs. Team owns rows [8t,8t+8); CU p owns units [32p,32p+32);
// wave w owns units [..+8w..). Weights VGPR-resident fp16 for the whole run.
// h handoff: RAW fp16, double-buffered, mantissa LSB = phase ((t>>1)&1)^1 —
// each 2-byte value self-describes freshness; relaxed AGENT atomics.
// [Session ledger: R1/R2/R4 scope variants starve/regress — agent scope
//  everywhere. R5 dual-team loses 2x CUs. R6 early-issue samples too early
//  (-630us: ~400cyc-earlier sample => ~1 extra retry RT/step — this is the
//  miss-cost calibration). R7 row-coalescing neutral. R8 register-direct h
//  amplifies requests 8x. R9 multi-sample retry neutral. R10 WIN (-130us):
//  single-store-per-sector publish — WRITE_SIZE 171->104MB confirms the
//  per-event invalidate/refetch model. R11 split-tile pipeline regressed
//  (+290us): extra mid-step barrier breaks MFMA scheduling.]
// R12 = R10 + terminal sleep 6->9: each sector is IF-refetched once/step
// regardless (FETCH evidence); a stale round-0 costs a SECOND serialized
// ~850cyc RT, while sleep costs 64cyc/unit on hit-steps. Asymmetry favors
// sampling later. Also: out-store moved off the gates->publish path.
// Poison 0xAAAA has LSB 0 != first expected phase 1 -> no init required.
// Step: poll(h(t-1)) -> barrier -> h-MFMAs -> gates -> stage-publish ->
// barrier -> wave0 sector stores -> filler (x rotate/prefetch + x-MFMA) ->
// s_sleep(9) -> loop.
template <bool XA>
__global__ __launch_bounds__(256, 1)
void lstm_persistent(const int* __restrict__ ids,
                     const int* __restrict__ seq_len,
                     const float* __restrict__ emb,
                     const float* __restrict__ w_ih,
                     const float* __restrict__ w_hh,
                     const float* __restrict__ b_ih,
                     const float* __restrict__ b_hh,
                     float* __restrict__ out,
                     _Float16* __restrict__ h16,      // [2][128][512] fp16
                     _Float16* __restrict__ x_all,    // [T][128][128] fp16
                     int* __restrict__ bar)
{
    __shared__ __align__(16) char smem[LDS_BYTES];
    unsigned* hsu = (unsigned*)smem;
    _Float16* hsh = (_Float16*)smem;
    float*    gs  = (float*)(smem + GOFF);
    unsigned short* pub = (unsigned short*)(smem + PUB_OFF);

    const int tid  = threadIdx.x;
    const int lane = tid & 63;
    const int wv   = tid >> 6;
    const int team = blockIdx.x & 15;
    const int p    = blockIdx.x >> 4;
    const int rowbase   = team * 8;
    const int unit_base = p * 32 + wv * 8;

    const int col  = lane & 15;   // MFMA n / C col
    const int kq   = lane >> 4;   // MFMA k-quad
    const int arow = lane & 7;    // A row (rows 8..15 duplicate 0..7)
    const int my_row  = lane >> 3;
    const int my_unit = unit_base + (lane & 7);

    if (XA) {
        // ---- phase 0: gather x_all[t][b][:] = fp16(emb[ids[t][b]][:]) ----
        for (int pair = blockIdx.x * 256 + tid; pair < TSEQ * BATCH;
             pair += 256 * 256) {
            const float* src = emb + (size_t)ids[pair] * DIN;   // pair = t*128+b
            _Float16* dst = x_all + (size_t)pair * DIN;
#pragma unroll
            for (int k = 0; k < 16; ++k) {
                float4v a = *(const float4v*)(src + k * 8);
                float4v c = *(const float4v*)(src + k * 8 + 4);
                *(half8*)(dst + k * 8) = cvt8(a, c);
            }
        }
        // ---- one-time grid barrier (full release/acquire, only here) ----
        __threadfence();
        __syncthreads();
        if (tid == 0) {
            __hip_atomic_fetch_add(bar, 1, __ATOMIC_RELEASE,
                                   __HIP_MEMORY_SCOPE_AGENT);
            int g = 0;
            while (__hip_atomic_load(bar, __ATOMIC_ACQUIRE,
                                     __HIP_MEMORY_SCOPE_AGENT) < 256
                   && ++g < (1 << 26)) { }
        }
        __syncthreads();
        __threadfence();
    }

    int tmax = 0, my_tstar = 0;
    for (int r = 0; r < 8; ++r) {
        int s  = seq_len[rowbase + r];
        int ts = (s > 0) ? (s - 1) : 0;
        if (r == my_row) my_tstar = ts;
        tmax = (ts > tmax) ? ts : tmax;
    }

    // ---- weight fragments -> VGPRs (fp32 -> fp16), once ----
    const int wrow0 = (col & 3) * HID + unit_base + (col >> 2);
    const int wrow1 = (col & 3) * HID + unit_base + 4 + (col >> 2);
    const float bias0 = b_ih[wrow0] + b_hh[wrow0];
    const float bias1 = b_ih[wrow1] + b_hh[wrow1];

    half8 whhf0[16], whhf1[16];
#pragma unroll
    for (int kt = 0; kt < 16; ++kt) {
        const float* s0 = w_hh + (size_t)wrow0 * HID + kt * 32 + kq * 8;
        const float* s1 = w_hh + (size_t)wrow1 * HID + kt * 32 + kq * 8;
        whhf0[kt] = cvt8(*(const float4v*)s0, *(const float4v*)(s0 + 4));
        whhf1[kt] = cvt8(*(const float4v*)s1, *(const float4v*)(s1 + 4));
    }
    half8 wihf0[4], wihf1[4];
#pragma unroll
    for (int kt = 0; kt < 4; ++kt) {
        const float* s0 = w_ih + (size_t)wrow0 * DIN + kt * 32 + kq * 8;
        const float* s1 = w_ih + (size_t)wrow1 * DIN + kt * 32 + kq * 8;
        wihf0[kt] = cvt8(*(const float4v*)s0, *(const float4v*)(s0 + 4));
        wihf1[kt] = cvt8(*(const float4v*)s1, *(const float4v*)(s1 + 4));
    }

    float c_state = 0.0f;
    const int crow = tid >> 5;    // poll/staging: row 0..7, 32 threads/row
    const int coff = tid & 31;    // thread polls u64s {coff + 32j}, j=0..3

    // ---- x fragment pipeline ----
    half8 xf[4], xn[4];
    if (XA) {
        const _Float16* x0 = x_all + ((size_t)0 * BATCH + rowbase + arow) * DIN;
        const int t1 = (tmax > 0) ? 1 : 0;
        const _Float16* x1 = x_all + ((size_t)t1 * BATCH + rowbase + arow) * DIN;
#pragma unroll
        for (int kt = 0; kt < 4; ++kt) {
            xf[kt] = *(const half8*)(x0 + kt * 32 + kq * 8);
            xn[kt] = *(const half8*)(x1 + kt * 32 + kq * 8);
        }
    } else {
        const int id0 = ids[rowbase + arow];
        const float* xrow = emb + (size_t)id0 * DIN;
#pragma unroll
        for (int kt = 0; kt < 4; ++kt) {
            const float* s = xrow + kt * 32 + kq * 8;
            xf[kt] = cvt8(*(const float4v*)s, *(const float4v*)(s + 4));
        }
    }

    // ---- acc(0) = bias + x(0) @ Wih, spread over 8 chains (a..d x 2) ----
    float4v a0 = {bias0, bias0, bias0, bias0}, b0 = {0,0,0,0}, c0 = {0,0,0,0}, d0 = {0,0,0,0};
    float4v a1 = {bias1, bias1, bias1, bias1}, b1 = {0,0,0,0}, c1 = {0,0,0,0}, d1 = {0,0,0,0};
    a0 = __builtin_amdgcn_mfma_f32_16x16x32_f16(xf[0], wihf0[0], a0, 0, 0, 0);
    b0 = __builtin_amdgcn_mfma_f32_16x16x32_f16(xf[1], wihf0[1], b0, 0, 0, 0);
    c0 = __builtin_amdgcn_mfma_f32_16x16x32_f16(xf[2], wihf0[2], c0, 0, 0, 0);
    d0 = __builtin_amdgcn_mfma_f32_16x16x32_f16(xf[3], wihf0[3], d0, 0, 0, 0);
    a1 = __builtin_amdgcn_mfma_f32_16x16x32_f16(xf[0], wihf1[0], a1, 0, 0, 0);
    b1 = __builtin_amdgcn_mfma_f32_16x16x32_f16(xf[1], wihf1[1], b1, 0, 0, 0);
    c1 = __builtin_amdgcn_mfma_f32_16x16x32_f16(xf[2], wihf1[2], c1, 0, 0, 0);
    d1 = __builtin_amdgcn_mfma_f32_16x16x32_f16(xf[3], wihf1[3], d1, 0, 0, 0);

    const u64 LSBM = 0x0001000100010001ull;

    for (int t = 0; t <= tmax; ++t) {
        const int bs = t & 1;    // LDS h-tile buffer for this step
        int id_next = 0;
        if (!XA) {
            const int tn = (t < tmax) ? (t + 1) : t;
            id_next = ids[tn * BATCH + rowbase + arow];
        }

        if (t > 0) {
            // ---- poll teammates' phase-tagged fp16 h (poll IS the load) ----
            const u64* rowp = (const u64*)(h16
                + (size_t)((t + 1) & 1) * BATCH * HID + (rowbase + crow) * HID);
            const u64 want = ((((t - 1) >> 1) & 1) ^ 1) ? LSBM : 0ull;
            unsigned* dstw = hsu + bs * HBUF_WORDS + crow * HW_STRIDE + 2 * coff;
            u64 v[4];
            unsigned pending = 0xF;
#pragma unroll
            for (int j = 0; j < 4; ++j)
                v[j] = __hip_atomic_load(rowp + coff + 32 * j,
                                         __ATOMIC_RELAXED, __HIP_MEMORY_SCOPE_AGENT);
#pragma unroll
            for (int j = 0; j < 4; ++j) {
                if (((v[j] ^ want) & LSBM) == 0) {
                    *(u64*)(dstw + 64 * j) = v[j];
                    pending &= ~(1u << j);
                }
            }
            int round = 0, guard = 0;
            while (pending) {
#pragma unroll
                for (int j = 0; j < 4; ++j) {
                    if (pending & (1u << j)) {
                        u64 x = __hip_atomic_load(rowp + coff + 32 * j,
                                                  __ATOMIC_RELAXED,
                                                  __HIP_MEMORY_SCOPE_AGENT);
                        if (((x ^ want) & LSBM) == 0) {
                            *(u64*)(dstw + 64 * j) = x;
                            pending &= ~(1u << j);
                        }
                    }
                }
                if (!pending) break;
                if (++round >= 3) __builtin_amdgcn_s_sleep(1);
                if (++guard > (1 << 20)) break;   // anti-hang safety valve
            }
        }
        __syncthreads();   // poll barrier (h-tile staged for all waves)

        float4v xraw[8];
        if (!XA) {
            // fallback: issue emb(t+1) raw loads here (h-MFMA shadow)
            const float* xrow = emb + (size_t)id_next * DIN;
#pragma unroll
            for (int kt = 0; kt < 4; ++kt) {
                xraw[2 * kt]     = *(const float4v*)(xrow + kt * 32 + kq * 8);
                xraw[2 * kt + 1] = *(const float4v*)(xrow + kt * 32 + kq * 8 + 4);
            }
        }

        if (t > 0) {
            // ---- h MFMAs: 16 kt over 8 chains (dependent depth 4) ----
            const _Float16* hb = hsh + bs * HBUF_WORDS * 2;
#pragma unroll
            for (int kt = 0; kt < 16; ++kt) {
                half8 af = *(const half8*)(hb + arow * (HW_STRIDE * 2) + kt * 32 + kq * 8);
                switch (kt & 3) {
                case 0:
                    a0 = __builtin_amdgcn_mfma_f32_16x16x32_f16(af, whhf0[kt], a0, 0, 0, 0);
                    a1 = __builtin_amdgcn_mfma_f32_16x16x32_f16(af, whhf1[kt], a1, 0, 0, 0);
                    break;
                case 1:
                    b0 = __builtin_amdgcn_mfma_f32_16x16x32_f16(af, whhf0[kt], b0, 0, 0, 0);
                    b1 = __builtin_amdgcn_mfma_f32_16x16x32_f16(af, whhf1[kt], b1, 0, 0, 0);
                    break;
                case 2:
                    c0 = __builtin_amdgcn_mfma_f32_16x16x32_f16(af, whhf0[kt], c0, 0, 0, 0);
                    c1 = __builtin_amdgcn_mfma_f32_16x16x32_f16(af, whhf1[kt], c1, 0, 0, 0);
                    break;
                default:
                    d0 = __builtin_amdgcn_mfma_f32_16x16x32_f16(af, whhf0[kt], d0, 0, 0, 0);
                    d1 = __builtin_amdgcn_mfma_f32_16x16x32_f16(af, whhf1[kt], d1, 0, 0, 0);
                }
            }
        }
        const float4v g0 = (a0 + b0) + (c0 + d0);
        const float4v g1 = (a1 + b1) + (c1 + d1);

        // ---- regroup i,f,g,o per (row,unit) via per-wave LDS scratch ----
        float* gw = gs + wv * 256;
        if (lane < 32) {
            const int grow = (lane >> 4) * 4;
#pragma unroll
            for (int r = 0; r < 4; ++r) {
                gw[(grow + r) * 32 + col]      = g0[r];
                gw[(grow + r) * 32 + 16 + col] = g1[r];
            }
        }
        const float4v g4 = *(const float4v*)(gw + my_row * 32 + (lane & 7) * 4);

        const float i_s = sigm(g4[0]);
        const float f_s = sigm(g4[1]);
        const float g_t = tanh_fast(g4[2]);
        const float o_s = sigm(g4[3]);
        c_state = f_s * c_state + i_s * g_t;
        const float hn = o_s * tanh_fast(c_state);

        // ---- publish h, SINGLE STORE PER SECTOR (R10): stage tagged fp16 in
        //      the block's LDS pub tile, barrier, then wave 0 stores 64
        //      coalesced u64s (each 64B sector written completely by 8
        //      adjacent lanes in one wave-instruction) ----
        {
            const unsigned pub_phase = (((unsigned)t >> 1) & 1u) ^ 1u;
            unsigned short hb16 = __builtin_bit_cast(unsigned short, (_Float16)hn);
            hb16 = (unsigned short)((hb16 & 0xFFFEu) | pub_phase);
            pub[my_row * 32 + wv * 8 + (lane & 7)] = hb16;
        }
        __syncthreads();   // publish-staging barrier
        if (tid < 64) {
            const int r = tid >> 3, seg = tid & 7;
            const u64 pk = *(const u64*)(pub + r * 32 + seg * 4);
            __hip_atomic_store((u64*)((unsigned short*)h16
                                   + (size_t)(t & 1) * BATCH * HID
                                   + (rowbase + r) * HID + p * 32) + seg,
                               pk, __ATOMIC_RELAXED, __HIP_MEMORY_SCOPE_AGENT);
        }

        // rare result write, off the gates->publish critical path
        if (t == my_tstar)
            out[(rowbase + my_row) * HID + my_unit] = c_state;

        // ---- filler between publish and next poll: x pipeline + x-MFMA(t+1)
        //      then the tuned s_sleep so poll round-0 samples past producer
        //      visibility ----
        if (XA) {
#pragma unroll
            for (int kt = 0; kt < 4; ++kt) xf[kt] = xn[kt];
            const int t2 = (t + 2 <= tmax) ? (t + 2) : tmax;
            const _Float16* xs2 = x_all + ((size_t)t2 * BATCH + rowbase + arow) * DIN;
#pragma unroll
            for (int kt = 0; kt < 4; ++kt)
                xn[kt] = *(const half8*)(xs2 + kt * 32 + kq * 8);
        } else {
#pragma unroll
            for (int kt = 0; kt < 4; ++kt)
                xf[kt] = cvt8(xraw[2 * kt], xraw[2 * kt + 1]);
        }

        a0 = (float4v){bias0, bias0, bias0, bias0}; b0 = (float4v){0,0,0,0};
        c0 = (float4v){0,0,0,0};                    d0 = (float4v){0,0,0,0};
        a1 = (float4v){bias1, bias1, bias1, bias1}; b1 = (float4v){0,0,0,0};
        c1 = (float4v){0,0,0,0};                    d1 = (float4v){0,0,0,0};
        a0 = __builtin_amdgcn_mfma_f32_16x16x32_f16(xf[0], wihf0[0], a0, 0, 0, 0);
        b0 = __builtin_amdgcn_mfma_f32_16x16x32_f16(xf[1], wihf0[1], b0, 0, 0, 0);
        c0 = __builtin_amdgcn_mfma_f32_16x16x32_f16(xf[2], wihf0[2], c0, 0, 0, 0);
        d0 = __builtin_amdgcn_mfma_f32_16x16x32_f16(xf[3], wihf0[3], d0, 0, 0, 0);
        a1 = __builtin_amdgcn_mfma_f32_16x16x32_f16(xf[0], wihf1[0], a1, 0, 0, 0);
        b1 = __builtin_amdgcn_mfma_f32_16x16x32_f16(xf[1], wihf1[1], b1, 0, 0, 0);
        c1 = __builtin_amdgcn_mfma_f32_16x16x32_f16(xf[2], wihf1[2], c1, 0, 0, 0);
        d1 = __builtin_amdgcn_mfma_f32_16x16x32_f16(xf[3], wihf1[3], d1, 0, 0, 0);

        // tuned pre-poll delay (R12: 6->9): stale round-0 costs a 2nd ~850cyc
        // RT; 3 extra sleep units (192cyc) are cheap insurance against it
        __builtin_amdgcn_s_sleep(9);
    }
}

extern "C" void kernel_launch(void* const* d_in, const int* in_sizes, int n_in,
                              void* d_out, int out_size, void* d_ws, size_t ws_size,
                              hipStream_t stream)
{
    const int*   ids  = (const int*)d_in[0];
    const int*   slen = (const int*)d_in[1];
    const float* emb  = (const float*)d_in[2];
    const float* wih  = (const float*)d_in[3];
    const float* whh  = (const float*)d_in[4];
    const float* bih  = (const float*)d_in[5];
    const float* bhh  = (const float*)d_in[6];
    float* out = (float*)d_out;

    _Float16* h16   = (_Float16*)((char*)d_ws + WS_H16_OFF);
    int*      bar   = (int*)((char*)d_ws + WS_BAR_OFF);
    _Float16* x_all = (_Float16*)((char*)d_ws + WS_XALL_OFF);

    if (ws_size >= WS_NEED) {
        hipMemsetAsync(bar, 0, sizeof(int), stream);
        hipLaunchKernelGGL((lstm_persistent<true>), dim3(256), dim3(256), 0, stream,
                           ids, slen, emb, wih, whh, bih, bhh, out,
                           h16, x_all, bar);
    } else {
        hipLaunchKernelGGL((lstm_persistent<false>), dim3(256), dim3(256), 0, stream,
                           ids, slen, emb, wih, whh, bih, bhh, out,
                           h16, x_all, bar);
    }
}

// Round 13
// 1917.622 us; speedup vs baseline: 1.1193x; 1.0044x over previous
//
#include <hip/hip_runtime.h>

typedef _Float16 half8 __attribute__((ext_vector_type(8)));
typedef float float4v __attribute__((ext_vector_type(4)));
typedef unsigned long long u64;

#define TSEQ  1024
#define BATCH 128
#define HID   512
#define DIN   128

// LDS: double-buffered h tile. Row stride 264 b32-words (528 halves) so the
// MFMA ds_read_b128 pattern lands 2-way max (free).
#define HW_STRIDE 264                        // b32 words per row
#define HBUF_WORDS (8 * HW_STRIDE)           // 2112 words per buffer
#define GOFF (2 * HBUF_WORDS * 4)            // 16896 B
#define LDS_BYTES (GOFF + 4 * 8 * 32 * 4)    // + per-wave gate scratch = 20992 B

// d_ws layout
#define WS_H16_OFF  0                                // [2][128][512] fp16 = 256 KiB
#define WS_BAR_OFF  (2 * BATCH * HID * 2)            // 262144
#define WS_XALL_OFF (1u << 20)                       // 1 MiB
#define WS_NEED     ((size_t)WS_XALL_OFF + (size_t)TSEQ * BATCH * DIN * 2)

#define HBUF_U64 (BATCH * HID / 4)           // u64s per h16 buffer (16384)

__device__ inline half8 cvt8(float4v a, float4v b) {
    half8 r;
    r[0] = (_Float16)a[0]; r[1] = (_Float16)a[1];
    r[2] = (_Float16)a[2]; r[3] = (_Float16)a[3];
    r[4] = (_Float16)b[0]; r[5] = (_Float16)b[1];
    r[6] = (_Float16)b[2]; r[7] = (_Float16)b[3];
    return r;
}

// branch-free sigmoid / tanh on v_exp_f32 + v_rcp_f32
__device__ inline float sigm(float x) {
    return __builtin_amdgcn_rcpf(1.0f + __builtin_amdgcn_exp2f(-1.44269504f * x));
}
__device__ inline float tanh_fast(float x) { return 2.0f * sigm(2.0f * x) - 1.0f; }

// 16 teams x 16 CUs. Team owns rows [8t,8t+8); CU p owns units [32p,32p+32);
// wave w owns units [..+8w..). Weights VGPR-resident fp16 for the whole run.
// h handoff: RAW fp16, double-buffered, mantissa LSB = phase ((t>>1)&1)^1 —
// each 2-byte value self-describes freshness; relaxed AGENT atomics.
// [Session ledger: R1/R2/R4 scope variants starve/regress — agent scope
//  everywhere. R5 dual-team loses 2x CUs. R6 early-issue samples ~400cyc too
//  early => ~1 extra retry RT/step (miss-cost calibration, -630us). R7
//  row-coalescing neutral. R8 register-direct h amplifies requests 8x.
//  R9 multi-sample retry neutral. R10 WIN (-130us): single-store-per-sector
//  publish — WRITE 171->104MB validates the per-event invalidate/refetch
//  model. R11 split-tile pipeline +290us (mid-step barrier breaks MFMA
//  scheduling). R12 sleep 9 +72us (sleep bracketed: 6 is optimal).]
// R13: WAVE-BLOCKED h16 LAYOUT — h16[buf][team][cu][wave][row][8u]. Each
// wave's 64 fp16 = one contiguous 128B run = 2 full sectors, stored by 16
// lanes in ONE wave-instruction (single event/sector preserved) right after
// that wave's gates: the publish-staging __syncthreads() is GONE (2
// barriers -> 1/step) and publish lands ~wave-skew earlier (more visibility
// slack before the next poll). Wave packs via its private LDS scratch
// (intra-wave lgkm ordering — R7-proven). Poll: same block-cooperative
// 1024-u64 read with remapped (loop-invariant) addresses; staging words
// remapped to keep the MFMA h-tile layout; same 2-way bank profile; retry
// loop / agent scope / phase protocol / sleep(6) unchanged.
// Poison 0xAAAA has LSB 0 != first expected phase 1 -> no init required.
// Step: poll(h(t-1)) -> barrier -> h-MFMAs -> gates -> per-wave publish ->
// out -> filler (x rotate/prefetch + x-MFMA(t+1)) -> s_sleep(6) -> loop.
template <bool XA>
__global__ __launch_bounds__(256, 1)
void lstm_persistent(const int* __restrict__ ids,
                     const int* __restrict__ seq_len,
                     const float* __restrict__ emb,
                     const float* __restrict__ w_ih,
                     const float* __restrict__ w_hh,
                     const float* __restrict__ b_ih,
                     const float* __restrict__ b_hh,
                     float* __restrict__ out,
                     _Float16* __restrict__ h16,      // [2][16][16][4][8][8] fp16
                     _Float16* __restrict__ x_all,    // [T][128][128] fp16
                     int* __restrict__ bar)
{
    __shared__ __align__(16) char smem[LDS_BYTES];
    unsigned* hsu = (unsigned*)smem;
    _Float16* hsh = (_Float16*)smem;
    float*    gs  = (float*)(smem + GOFF);

    const int tid  = threadIdx.x;
    const int lane = tid & 63;
    const int wv   = tid >> 6;
    const int team = blockIdx.x & 15;
    const int p    = blockIdx.x >> 4;
    const int rowbase   = team * 8;
    const int unit_base = p * 32 + wv * 8;

    const int col  = lane & 15;   // MFMA n / C col
    const int kq   = lane >> 4;   // MFMA k-quad
    const int arow = lane & 7;    // A row (rows 8..15 duplicate 0..7)
    const int my_row  = lane >> 3;
    const int my_unit = unit_base + (lane & 7);

    if (XA) {
        // ---- phase 0: gather x_all[t][b][:] = fp16(emb[ids[t][b]][:]) ----
        for (int pair = blockIdx.x * 256 + tid; pair < TSEQ * BATCH;
             pair += 256 * 256) {
            const float* src = emb + (size_t)ids[pair] * DIN;   // pair = t*128+b
            _Float16* dst = x_all + (size_t)pair * DIN;
#pragma unroll
            for (int k = 0; k < 16; ++k) {
                float4v a = *(const float4v*)(src + k * 8);
                float4v c = *(const float4v*)(src + k * 8 + 4);
                *(half8*)(dst + k * 8) = cvt8(a, c);
            }
        }
        // ---- one-time grid barrier (full release/acquire, only here) ----
        __threadfence();
        __syncthreads();
        if (tid == 0) {
            __hip_atomic_fetch_add(bar, 1, __ATOMIC_RELEASE,
                                   __HIP_MEMORY_SCOPE_AGENT);
            int g = 0;
            while (__hip_atomic_load(bar, __ATOMIC_ACQUIRE,
                                     __HIP_MEMORY_SCOPE_AGENT) < 256
                   && ++g < (1 << 26)) { }
        }
        __syncthreads();
        __threadfence();
    }

    int tmax = 0, my_tstar = 0;
    for (int r = 0; r < 8; ++r) {
        int s  = seq_len[rowbase + r];
        int ts = (s > 0) ? (s - 1) : 0;
        if (r == my_row) my_tstar = ts;
        tmax = (ts > tmax) ? ts : tmax;
    }

    // ---- weight fragments -> VGPRs (fp32 -> fp16), once ----
    const int wrow0 = (col & 3) * HID + unit_base + (col >> 2);
    const int wrow1 = (col & 3) * HID + unit_base + 4 + (col >> 2);
    const float bias0 = b_ih[wrow0] + b_hh[wrow0];
    const float bias1 = b_ih[wrow1] + b_hh[wrow1];

    half8 whhf0[16], whhf1[16];
#pragma unroll
    for (int kt = 0; kt < 16; ++kt) {
        const float* s0 = w_hh + (size_t)wrow0 * HID + kt * 32 + kq * 8;
        const float* s1 = w_hh + (size_t)wrow1 * HID + kt * 32 + kq * 8;
        whhf0[kt] = cvt8(*(const float4v*)s0, *(const float4v*)(s0 + 4));
        whhf1[kt] = cvt8(*(const float4v*)s1, *(const float4v*)(s1 + 4));
    }
    half8 wihf0[4], wihf1[4];
#pragma unroll
    for (int kt = 0; kt < 4; ++kt) {
        const float* s0 = w_ih + (size_t)wrow0 * DIN + kt * 32 + kq * 8;
        const float* s1 = w_ih + (size_t)wrow1 * DIN + kt * 32 + kq * 8;
        wihf0[kt] = cvt8(*(const float4v*)s0, *(const float4v*)(s0 + 4));
        wihf1[kt] = cvt8(*(const float4v*)s1, *(const float4v*)(s1 + 4));
    }

    float c_state = 0.0f;
    const int crow = tid >> 5;    // poll/staging: row 0..7, 32 threads/row
    const int coff = tid & 31;    // thread polls 4 u64 slots (see map below)

    // ---- poll address map (loop-invariant): slot g = coff + 32j covers
    //      (cu = g>>3, wave = (g>>1)&3, half = g&1) of row crow ----
    int pidx[4];   // u64 index inside the team's 1024-u64 tile
    int pwrd[4];   // b32 word offset inside the staged LDS h-tile row
#pragma unroll
    for (int j = 0; j < 4; ++j) {
        const int g  = coff + 32 * j;
        const int pp = g >> 3, ww = (g >> 1) & 3, hf = g & 1;
        pidx[j] = pp * 64 + ww * 16 + crow * 2 + hf;
        pwrd[j] = pp * 16 + ww * 4 + hf * 2;
    }

    // ---- x fragment pipeline ----
    half8 xf[4], xn[4];
    if (XA) {
        const _Float16* x0 = x_all + ((size_t)0 * BATCH + rowbase + arow) * DIN;
        const int t1 = (tmax > 0) ? 1 : 0;
        const _Float16* x1 = x_all + ((size_t)t1 * BATCH + rowbase + arow) * DIN;
#pragma unroll
        for (int kt = 0; kt < 4; ++kt) {
            xf[kt] = *(const half8*)(x0 + kt * 32 + kq * 8);
            xn[kt] = *(const half8*)(x1 + kt * 32 + kq * 8);
        }
    } else {
        const int id0 = ids[rowbase + arow];
        const float* xrow = emb + (size_t)id0 * DIN;
#pragma unroll
        for (int kt = 0; kt < 4; ++kt) {
            const float* s = xrow + kt * 32 + kq * 8;
            xf[kt] = cvt8(*(const float4v*)s, *(const float4v*)(s + 4));
        }
    }

    // ---- acc(0) = bias + x(0) @ Wih, spread over 8 chains (a..d x 2) ----
    float4v a0 = {bias0, bias0, bias0, bias0}, b0 = {0,0,0,0}, c0 = {0,0,0,0}, d0 = {0,0,0,0};
    float4v a1 = {bias1, bias1, bias1, bias1}, b1 = {0,0,0,0}, c1 = {0,0,0,0}, d1 = {0,0,0,0};
    a0 = __builtin_amdgcn_mfma_f32_16x16x32_f16(xf[0], wihf0[0], a0, 0, 0, 0);
    b0 = __builtin_amdgcn_mfma_f32_16x16x32_f16(xf[1], wihf0[1], b0, 0, 0, 0);
    c0 = __builtin_amdgcn_mfma_f32_16x16x32_f16(xf[2], wihf0[2], c0, 0, 0, 0);
    d0 = __builtin_amdgcn_mfma_f32_16x16x32_f16(xf[3], wihf0[3], d0, 0, 0, 0);
    a1 = __builtin_amdgcn_mfma_f32_16x16x32_f16(xf[0], wihf1[0], a1, 0, 0, 0);
    b1 = __builtin_amdgcn_mfma_f32_16x16x32_f16(xf[1], wihf1[1], b1, 0, 0, 0);
    c1 = __builtin_amdgcn_mfma_f32_16x16x32_f16(xf[2], wihf1[2], c1, 0, 0, 0);
    d1 = __builtin_amdgcn_mfma_f32_16x16x32_f16(xf[3], wihf1[3], d1, 0, 0, 0);

    const u64 LSBM = 0x0001000100010001ull;

    for (int t = 0; t <= tmax; ++t) {
        const int bs = t & 1;    // LDS h-tile buffer for this step
        int id_next = 0;
        if (!XA) {
            const int tn = (t < tmax) ? (t + 1) : t;
            id_next = ids[tn * BATCH + rowbase + arow];
        }

        if (t > 0) {
            // ---- poll teammates' phase-tagged fp16 h (poll IS the load) ----
            const u64* tb = (const u64*)h16
                + (size_t)((t + 1) & 1) * HBUF_U64 + team * 1024;
            const u64 want = ((((t - 1) >> 1) & 1) ^ 1) ? LSBM : 0ull;
            unsigned* dstw = hsu + bs * HBUF_WORDS + crow * HW_STRIDE;
            u64 v[4];
            unsigned pending = 0xF;
#pragma unroll
            for (int j = 0; j < 4; ++j)
                v[j] = __hip_atomic_load(tb + pidx[j],
                                         __ATOMIC_RELAXED, __HIP_MEMORY_SCOPE_AGENT);
#pragma unroll
            for (int j = 0; j < 4; ++j) {
                if (((v[j] ^ want) & LSBM) == 0) {
                    *(u64*)(dstw + pwrd[j]) = v[j];
                    pending &= ~(1u << j);
                }
            }
            int round = 0, guard = 0;
            while (pending) {
#pragma unroll
                for (int j = 0; j < 4; ++j) {
                    if (pending & (1u << j)) {
                        u64 x = __hip_atomic_load(tb + pidx[j],
                                                  __ATOMIC_RELAXED,
                                                  __HIP_MEMORY_SCOPE_AGENT);
                        if (((x ^ want) & LSBM) == 0) {
                            *(u64*)(dstw + pwrd[j]) = x;
                            pending &= ~(1u << j);
                        }
                    }
                }
                if (!pending) break;
                if (++round >= 3) __builtin_amdgcn_s_sleep(1);
                if (++guard > (1 << 20)) break;   // anti-hang safety valve
            }
        }
        __syncthreads();   // the ONLY barrier per step (h-tile double-buffered)

        float4v xraw[8];
        if (!XA) {
            // fallback: issue emb(t+1) raw loads here (h-MFMA shadow)
            const float* xrow = emb + (size_t)id_next * DIN;
#pragma unroll
            for (int kt = 0; kt < 4; ++kt) {
                xraw[2 * kt]     = *(const float4v*)(xrow + kt * 32 + kq * 8);
                xraw[2 * kt + 1] = *(const float4v*)(xrow + kt * 32 + kq * 8 + 4);
            }
        }

        if (t > 0) {
            // ---- h MFMAs: 16 kt over 8 chains (dependent depth 4) ----
            const _Float16* hb = hsh + bs * HBUF_WORDS * 2;
#pragma unroll
            for (int kt = 0; kt < 16; ++kt) {
                half8 af = *(const half8*)(hb + arow * (HW_STRIDE * 2) + kt * 32 + kq * 8);
                switch (kt & 3) {
                case 0:
                    a0 = __builtin_amdgcn_mfma_f32_16x16x32_f16(af, whhf0[kt], a0, 0, 0, 0);
                    a1 = __builtin_amdgcn_mfma_f32_16x16x32_f16(af, whhf1[kt], a1, 0, 0, 0);
                    break;
                case 1:
                    b0 = __builtin_amdgcn_mfma_f32_16x16x32_f16(af, whhf0[kt], b0, 0, 0, 0);
                    b1 = __builtin_amdgcn_mfma_f32_16x16x32_f16(af, whhf1[kt], b1, 0, 0, 0);
                    break;
                case 2:
                    c0 = __builtin_amdgcn_mfma_f32_16x16x32_f16(af, whhf0[kt], c0, 0, 0, 0);
                    c1 = __builtin_amdgcn_mfma_f32_16x16x32_f16(af, whhf1[kt], c1, 0, 0, 0);
                    break;
                default:
                    d0 = __builtin_amdgcn_mfma_f32_16x16x32_f16(af, whhf0[kt], d0, 0, 0, 0);
                    d1 = __builtin_amdgcn_mfma_f32_16x16x32_f16(af, whhf1[kt], d1, 0, 0, 0);
                }
            }
        }
        const float4v g0 = (a0 + b0) + (c0 + d0);
        const float4v g1 = (a1 + b1) + (c1 + d1);

        // ---- regroup i,f,g,o per (row,unit) via per-wave LDS scratch ----
        float* gw = gs + wv * 256;
        if (lane < 32) {
            const int grow = (lane >> 4) * 4;
#pragma unroll
            for (int r = 0; r < 4; ++r) {
                gw[(grow + r) * 32 + col]      = g0[r];
                gw[(grow + r) * 32 + 16 + col] = g1[r];
            }
        }
        const float4v g4 = *(const float4v*)(gw + my_row * 32 + (lane & 7) * 4);

        const float i_s = sigm(g4[0]);
        const float f_s = sigm(g4[1]);
        const float g_t = tanh_fast(g4[2]);
        const float o_s = sigm(g4[3]);
        c_state = f_s * c_state + i_s * g_t;
        const float hn = o_s * tanh_fast(c_state);

        // ---- per-wave publish (R13): pack the wave's 64 tagged fp16 in its
        //      PRIVATE LDS scratch (intra-wave lgkm order, no barrier), then
        //      16 lanes store 16 u64s = the wave's contiguous 128B run =
        //      2 full sectors in ONE wave-instruction ----
        {
            const unsigned pub_phase = (((unsigned)t >> 1) & 1u) ^ 1u;
            unsigned short hb16 = __builtin_bit_cast(unsigned short, (_Float16)hn);
            hb16 = (unsigned short)((hb16 & 0xFFFEu) | pub_phase);
            unsigned short* ps = (unsigned short*)gw;    // 128B wave staging
            ps[my_row * 8 + (lane & 7)] = hb16;
            if (lane < 16) {
                const u64 pk = *(const u64*)(ps + 4 * lane);
                u64* dst = (u64*)h16 + (size_t)(t & 1) * HBUF_U64
                           + team * 1024 + p * 64 + wv * 16 + lane;
                __hip_atomic_store(dst, pk, __ATOMIC_RELAXED,
                                   __HIP_MEMORY_SCOPE_AGENT);
            }
        }

        if (t == my_tstar)
            out[(rowbase + my_row) * HID + my_unit] = c_state;

        // ---- filler between publish and next poll: x pipeline + x-MFMA(t+1)
        //      then the tuned s_sleep so poll round-0 samples past producer
        //      visibility ----
        if (XA) {
#pragma unroll
            for (int kt = 0; kt < 4; ++kt) xf[kt] = xn[kt];
            const int t2 = (t + 2 <= tmax) ? (t + 2) : tmax;
            const _Float16* xs2 = x_all + ((size_t)t2 * BATCH + rowbase + arow) * DIN;
#pragma unroll
            for (int kt = 0; kt < 4; ++kt)
                xn[kt] = *(const half8*)(xs2 + kt * 32 + kq * 8);
        } else {
#pragma unroll
            for (int kt = 0; kt < 4; ++kt)
                xf[kt] = cvt8(xraw[2 * kt], xraw[2 * kt + 1]);
        }

        a0 = (float4v){bias0, bias0, bias0, bias0}; b0 = (float4v){0,0,0,0};
        c0 = (float4v){0,0,0,0};                    d0 = (float4v){0,0,0,0};
        a1 = (float4v){bias1, bias1, bias1, bias1}; b1 = (float4v){0,0,0,0};
        c1 = (float4v){0,0,0,0};                    d1 = (float4v){0,0,0,0};
        a0 = __builtin_amdgcn_mfma_f32_16x16x32_f16(xf[0], wihf0[0], a0, 0, 0, 0);
        b0 = __builtin_amdgcn_mfma_f32_16x16x32_f16(xf[1], wihf0[1], b0, 0, 0, 0);
        c0 = __builtin_amdgcn_mfma_f32_16x16x32_f16(xf[2], wihf0[2], c0, 0, 0, 0);
        d0 = __builtin_amdgcn_mfma_f32_16x16x32_f16(xf[3], wihf0[3], d0, 0, 0, 0);
        a1 = __builtin_amdgcn_mfma_f32_16x16x32_f16(xf[0], wihf1[0], a1, 0, 0, 0);
        b1 = __builtin_amdgcn_mfma_f32_16x16x32_f16(xf[1], wihf1[1], b1, 0, 0, 0);
        c1 = __builtin_amdgcn_mfma_f32_16x16x32_f16(xf[2], wihf1[2], c1, 0, 0, 0);
        d1 = __builtin_amdgcn_mfma_f32_16x16x32_f16(xf[3], wihf1[3], d1, 0, 0, 0);

        // tuned pre-poll delay: ~384 cyc (bracketed optimal: R6/R3/R12)
        __builtin_amdgcn_s_sleep(6);
    }
}

extern "C" void kernel_launch(void* const* d_in, const int* in_sizes, int n_in,
                              void* d_out, int out_size, void* d_ws, size_t ws_size,
                              hipStream_t stream)
{
    const int*   ids  = (const int*)d_in[0];
    const int*   slen = (const int*)d_in[1];
    const float* emb  = (const float*)d_in[2];
    const float* wih  = (const float*)d_in[3];
    const float* whh  = (const float*)d_in[4];
    const float* bih  = (const float*)d_in[5];
    const float* bhh  = (const float*)d_in[6];
    float* out = (float*)d_out;

    _Float16* h16   = (_Float16*)((char*)d_ws + WS_H16_OFF);
    int*      bar   = (int*)((char*)d_ws + WS_BAR_OFF);
    _Float16* x_all = (_Float16*)((char*)d_ws + WS_XALL_OFF);

    if (ws_size >= WS_NEED) {
        hipMemsetAsync(bar, 0, sizeof(int), stream);
        hipLaunchKernelGGL((lstm_persistent<true>), dim3(256), dim3(256), 0, stream,
                           ids, slen, emb, wih, whh, bih, bhh, out,
                           h16, x_all, bar);
    } else {
        hipLaunchKernelGGL((lstm_persistent<false>), dim3(256), dim3(256), 0, stream,
                           ids, slen, emb, wih, whh, bih, bhh, out,
                           h16, x_all, bar);
    }
}

// Round 14
// 1798.268 us; speedup vs baseline: 1.1936x; 1.0664x over previous
//
#include <hip/hip_runtime.h>

typedef _Float16 half8 __attribute__((ext_vector_type(8)));
typedef float float4v __attribute__((ext_vector_type(4)));
typedef unsigned long long u64;

#define TSEQ  1024
#define BATCH 128
#define HID   512
#define DIN   128

// LDS: double-buffered h tile. Row stride 264 b32-words (528 halves) so the
// MFMA ds_read_b128 pattern lands 2-way max (free).
#define HW_STRIDE 264                        // b32 words per row
#define HBUF_WORDS (8 * HW_STRIDE)           // 2112 words per buffer
#define GOFF (2 * HBUF_WORDS * 4)            // 16896 B
#define LDS_BYTES (GOFF + 4 * 8 * 32 * 4)    // + per-wave gate scratch = 20992 B

// d_ws layout
#define WS_H16_OFF  0                                // [2][128][512] fp16 = 256 KiB
#define WS_BAR_OFF  (2 * BATCH * HID * 2)            // 262144
#define WS_XALL_OFF (1u << 20)                       // 1 MiB
#define WS_NEED     ((size_t)WS_XALL_OFF + (size_t)TSEQ * BATCH * DIN * 2)

#define HBUF_U64 (BATCH * HID / 4)           // u64s per h16 buffer (16384)

__device__ inline half8 cvt8(float4v a, float4v b) {
    half8 r;
    r[0] = (_Float16)a[0]; r[1] = (_Float16)a[1];
    r[2] = (_Float16)a[2]; r[3] = (_Float16)a[3];
    r[4] = (_Float16)b[0]; r[5] = (_Float16)b[1];
    r[6] = (_Float16)b[2]; r[7] = (_Float16)b[3];
    return r;
}

// branch-free sigmoid / tanh on v_exp_f32 + v_rcp_f32
__device__ inline float sigm(float x) {
    return __builtin_amdgcn_rcpf(1.0f + __builtin_amdgcn_exp2f(-1.44269504f * x));
}
__device__ inline float tanh_fast(float x) { return 2.0f * sigm(2.0f * x) - 1.0f; }

// 16 teams x 16 CUs. Team owns rows [8t,8t+8); CU p owns units [32p,32p+32);
// wave w owns units [..+8w..). Weights VGPR-resident fp16 for the whole run.
// h handoff: RAW fp16, double-buffered, mantissa LSB = phase ((t>>1)&1)^1 —
// each 2-byte value self-describes freshness; relaxed AGENT atomics.
// [Session ledger: R1/R2/R4 scope variants starve/regress — agent scope
//  everywhere. R5 dual-team loses 2x CUs. R6 early-issue samples ~400cyc too
//  early => ~1 extra retry RT/step (-630us; miss-cost calibration). R7
//  row-coalescing neutral. R8 register-direct h amplifies requests 8x.
//  R9 multi-sample retry neutral. R10 WIN (-130us): single-store-per-sector
//  publish — WRITE 171->104MB validates per-event invalidate/refetch model.
//  R11 split-tile pipeline +290us. R12 sleep 9 +72us (sleep 6 optimal).
//  R13 wave-blocked layout +64us vs R10 — barrier removal fine, but the
//  remapped poll scattered lanes to 8B pieces 128B apart.]
// R14 = R13 layout + COALESCED poll map. h16[buf][team][cu][wave][row][hf]:
//  - publish: each wave packs its 64 tagged fp16 via its PRIVATE gate
//    scratch (intra-wave lgkm order) and 16 lanes store one contiguous
//    128B run = 2 full sectors in ONE wave-instruction. Single event per
//    sector (R10's win), NO publish barrier (R13's win), lands right after
//    each wave's gates (earlier than R10's block-staged publish).
//  - poll: thread tid reads u64 slots g = tid + 256j — each wave reads 64
//    CONSECUTIVE u64s = 512B contiguous (beats R10's 256B row runs).
//    LDS stage word for g: row(g)*264 + cu(g)*16 + wv(g)*4 + hf(g)*2;
//    bank = (8(row&3)+4wv+2hf)%32 -> 2-way max (free).
// Poison 0xAAAA has LSB 0 != first expected phase 1 -> no init required.
// Step: poll(h(t-1)) -> barrier -> h-MFMAs -> gates -> per-wave publish ->
// out -> filler (x rotate/prefetch + x-MFMA(t+1)) -> s_sleep(6) -> loop.
template <bool XA>
__global__ __launch_bounds__(256, 1)
void lstm_persistent(const int* __restrict__ ids,
                     const int* __restrict__ seq_len,
                     const float* __restrict__ emb,
                     const float* __restrict__ w_ih,
                     const float* __restrict__ w_hh,
                     const float* __restrict__ b_ih,
                     const float* __restrict__ b_hh,
                     float* __restrict__ out,
                     _Float16* __restrict__ h16,      // [2][16][16][4][8][2] u64 view
                     _Float16* __restrict__ x_all,    // [T][128][128] fp16
                     int* __restrict__ bar)
{
    __shared__ __align__(16) char smem[LDS_BYTES];
    unsigned* hsu = (unsigned*)smem;
    _Float16* hsh = (_Float16*)smem;
    float*    gs  = (float*)(smem + GOFF);

    const int tid  = threadIdx.x;
    const int lane = tid & 63;
    const int wv   = tid >> 6;
    const int team = blockIdx.x & 15;
    const int p    = blockIdx.x >> 4;
    const int rowbase   = team * 8;
    const int unit_base = p * 32 + wv * 8;

    const int col  = lane & 15;   // MFMA n / C col
    const int kq   = lane >> 4;   // MFMA k-quad
    const int arow = lane & 7;    // A row (rows 8..15 duplicate 0..7)
    const int my_row  = lane >> 3;
    const int my_unit = unit_base + (lane & 7);

    if (XA) {
        // ---- phase 0: gather x_all[t][b][:] = fp16(emb[ids[t][b]][:]) ----
        for (int pair = blockIdx.x * 256 + tid; pair < TSEQ * BATCH;
             pair += 256 * 256) {
            const float* src = emb + (size_t)ids[pair] * DIN;   // pair = t*128+b
            _Float16* dst = x_all + (size_t)pair * DIN;
#pragma unroll
            for (int k = 0; k < 16; ++k) {
                float4v a = *(const float4v*)(src + k * 8);
                float4v c = *(const float4v*)(src + k * 8 + 4);
                *(half8*)(dst + k * 8) = cvt8(a, c);
            }
        }
        // ---- one-time grid barrier (full release/acquire, only here) ----
        __threadfence();
        __syncthreads();
        if (tid == 0) {
            __hip_atomic_fetch_add(bar, 1, __ATOMIC_RELEASE,
                                   __HIP_MEMORY_SCOPE_AGENT);
            int g = 0;
            while (__hip_atomic_load(bar, __ATOMIC_ACQUIRE,
                                     __HIP_MEMORY_SCOPE_AGENT) < 256
                   && ++g < (1 << 26)) { }
        }
        __syncthreads();
        __threadfence();
    }

    int tmax = 0, my_tstar = 0;
    for (int r = 0; r < 8; ++r) {
        int s  = seq_len[rowbase + r];
        int ts = (s > 0) ? (s - 1) : 0;
        if (r == my_row) my_tstar = ts;
        tmax = (ts > tmax) ? ts : tmax;
    }

    // ---- weight fragments -> VGPRs (fp32 -> fp16), once ----
    const int wrow0 = (col & 3) * HID + unit_base + (col >> 2);
    const int wrow1 = (col & 3) * HID + unit_base + 4 + (col >> 2);
    const float bias0 = b_ih[wrow0] + b_hh[wrow0];
    const float bias1 = b_ih[wrow1] + b_hh[wrow1];

    half8 whhf0[16], whhf1[16];
#pragma unroll
    for (int kt = 0; kt < 16; ++kt) {
        const float* s0 = w_hh + (size_t)wrow0 * HID + kt * 32 + kq * 8;
        const float* s1 = w_hh + (size_t)wrow1 * HID + kt * 32 + kq * 8;
        whhf0[kt] = cvt8(*(const float4v*)s0, *(const float4v*)(s0 + 4));
        whhf1[kt] = cvt8(*(const float4v*)s1, *(const float4v*)(s1 + 4));
    }
    half8 wihf0[4], wihf1[4];
#pragma unroll
    for (int kt = 0; kt < 4; ++kt) {
        const float* s0 = w_ih + (size_t)wrow0 * DIN + kt * 32 + kq * 8;
        const float* s1 = w_ih + (size_t)wrow1 * DIN + kt * 32 + kq * 8;
        wihf0[kt] = cvt8(*(const float4v*)s0, *(const float4v*)(s0 + 4));
        wihf1[kt] = cvt8(*(const float4v*)s1, *(const float4v*)(s1 + 4));
    }

    float c_state = 0.0f;

    // ---- poll map (loop-invariant, coalesced): slot g = tid + 256j;
    //      g = cu*64 + wv*16 + row*2 + hf (wave-blocked tile order) ----
    int pwrd[4];
#pragma unroll
    for (int j = 0; j < 4; ++j) {
        const int g = tid + 256 * j;
        const int cu = g >> 6, ww = (g >> 4) & 3, rr = (g >> 1) & 7, hf = g & 1;
        pwrd[j] = rr * HW_STRIDE + cu * 16 + ww * 4 + hf * 2;
    }

    // ---- x fragment pipeline ----
    half8 xf[4], xn[4];
    if (XA) {
        const _Float16* x0 = x_all + ((size_t)0 * BATCH + rowbase + arow) * DIN;
        const int t1 = (tmax > 0) ? 1 : 0;
        const _Float16* x1 = x_all + ((size_t)t1 * BATCH + rowbase + arow) * DIN;
#pragma unroll
        for (int kt = 0; kt < 4; ++kt) {
            xf[kt] = *(const half8*)(x0 + kt * 32 + kq * 8);
            xn[kt] = *(const half8*)(x1 + kt * 32 + kq * 8);
        }
    } else {
        const int id0 = ids[rowbase + arow];
        const float* xrow = emb + (size_t)id0 * DIN;
#pragma unroll
        for (int kt = 0; kt < 4; ++kt) {
            const float* s = xrow + kt * 32 + kq * 8;
            xf[kt] = cvt8(*(const float4v*)s, *(const float4v*)(s + 4));
        }
    }

    // ---- acc(0) = bias + x(0) @ Wih, spread over 8 chains (a..d x 2) ----
    float4v a0 = {bias0, bias0, bias0, bias0}, b0 = {0,0,0,0}, c0 = {0,0,0,0}, d0 = {0,0,0,0};
    float4v a1 = {bias1, bias1, bias1, bias1}, b1 = {0,0,0,0}, c1 = {0,0,0,0}, d1 = {0,0,0,0};
    a0 = __builtin_amdgcn_mfma_f32_16x16x32_f16(xf[0], wihf0[0], a0, 0, 0, 0);
    b0 = __builtin_amdgcn_mfma_f32_16x16x32_f16(xf[1], wihf0[1], b0, 0, 0, 0);
    c0 = __builtin_amdgcn_mfma_f32_16x16x32_f16(xf[2], wihf0[2], c0, 0, 0, 0);
    d0 = __builtin_amdgcn_mfma_f32_16x16x32_f16(xf[3], wihf0[3], d0, 0, 0, 0);
    a1 = __builtin_amdgcn_mfma_f32_16x16x32_f16(xf[0], wihf1[0], a1, 0, 0, 0);
    b1 = __builtin_amdgcn_mfma_f32_16x16x32_f16(xf[1], wihf1[1], b1, 0, 0, 0);
    c1 = __builtin_amdgcn_mfma_f32_16x16x32_f16(xf[2], wihf1[2], c1, 0, 0, 0);
    d1 = __builtin_amdgcn_mfma_f32_16x16x32_f16(xf[3], wihf1[3], d1, 0, 0, 0);

    const u64 LSBM = 0x0001000100010001ull;

    for (int t = 0; t <= tmax; ++t) {
        const int bs = t & 1;    // LDS h-tile buffer for this step
        int id_next = 0;
        if (!XA) {
            const int tn = (t < tmax) ? (t + 1) : t;
            id_next = ids[tn * BATCH + rowbase + arow];
        }

        if (t > 0) {
            // ---- poll teammates' phase-tagged fp16 h (poll IS the load) ----
            const u64* tb = (const u64*)h16
                + (size_t)((t + 1) & 1) * HBUF_U64 + team * 1024;
            const u64 want = ((((t - 1) >> 1) & 1) ^ 1) ? LSBM : 0ull;
            unsigned* dstw = hsu + bs * HBUF_WORDS;
            u64 v[4];
            unsigned pending = 0xF;
#pragma unroll
            for (int j = 0; j < 4; ++j)
                v[j] = __hip_atomic_load(tb + tid + 256 * j,
                                         __ATOMIC_RELAXED, __HIP_MEMORY_SCOPE_AGENT);
#pragma unroll
            for (int j = 0; j < 4; ++j) {
                if (((v[j] ^ want) & LSBM) == 0) {
                    *(u64*)(dstw + pwrd[j]) = v[j];
                    pending &= ~(1u << j);
                }
            }
            int round = 0, guard = 0;
            while (pending) {
#pragma unroll
                for (int j = 0; j < 4; ++j) {
                    if (pending & (1u << j)) {
                        u64 x = __hip_atomic_load(tb + tid + 256 * j,
                                                  __ATOMIC_RELAXED,
                                                  __HIP_MEMORY_SCOPE_AGENT);
                        if (((x ^ want) & LSBM) == 0) {
                            *(u64*)(dstw + pwrd[j]) = x;
                            pending &= ~(1u << j);
                        }
                    }
                }
                if (!pending) break;
                if (++round >= 3) __builtin_amdgcn_s_sleep(1);
                if (++guard > (1 << 20)) break;   // anti-hang safety valve
            }
        }
        __syncthreads();   // the ONLY barrier per step (h-tile double-buffered)

        float4v xraw[8];
        if (!XA) {
            // fallback: issue emb(t+1) raw loads here (h-MFMA shadow)
            const float* xrow = emb + (size_t)id_next * DIN;
#pragma unroll
            for (int kt = 0; kt < 4; ++kt) {
                xraw[2 * kt]     = *(const float4v*)(xrow + kt * 32 + kq * 8);
                xraw[2 * kt + 1] = *(const float4v*)(xrow + kt * 32 + kq * 8 + 4);
            }
        }

        if (t > 0) {
            // ---- h MFMAs: 16 kt over 8 chains (dependent depth 4) ----
            const _Float16* hb = hsh + bs * HBUF_WORDS * 2;
#pragma unroll
            for (int kt = 0; kt < 16; ++kt) {
                half8 af = *(const half8*)(hb + arow * (HW_STRIDE * 2) + kt * 32 + kq * 8);
                switch (kt & 3) {
                case 0:
                    a0 = __builtin_amdgcn_mfma_f32_16x16x32_f16(af, whhf0[kt], a0, 0, 0, 0);
                    a1 = __builtin_amdgcn_mfma_f32_16x16x32_f16(af, whhf1[kt], a1, 0, 0, 0);
                    break;
                case 1:
                    b0 = __builtin_amdgcn_mfma_f32_16x16x32_f16(af, whhf0[kt], b0, 0, 0, 0);
                    b1 = __builtin_amdgcn_mfma_f32_16x16x32_f16(af, whhf1[kt], b1, 0, 0, 0);
                    break;
                case 2:
                    c0 = __builtin_amdgcn_mfma_f32_16x16x32_f16(af, whhf0[kt], c0, 0, 0, 0);
                    c1 = __builtin_amdgcn_mfma_f32_16x16x32_f16(af, whhf1[kt], c1, 0, 0, 0);
                    break;
                default:
                    d0 = __builtin_amdgcn_mfma_f32_16x16x32_f16(af, whhf0[kt], d0, 0, 0, 0);
                    d1 = __builtin_amdgcn_mfma_f32_16x16x32_f16(af, whhf1[kt], d1, 0, 0, 0);
                }
            }
        }
        const float4v g0 = (a0 + b0) + (c0 + d0);
        const float4v g1 = (a1 + b1) + (c1 + d1);

        // ---- regroup i,f,g,o per (row,unit) via per-wave LDS scratch ----
        float* gw = gs + wv * 256;
        if (lane < 32) {
            const int grow = (lane >> 4) * 4;
#pragma unroll
            for (int r = 0; r < 4; ++r) {
                gw[(grow + r) * 32 + col]      = g0[r];
                gw[(grow + r) * 32 + 16 + col] = g1[r];
            }
        }
        const float4v g4 = *(const float4v*)(gw + my_row * 32 + (lane & 7) * 4);

        const float i_s = sigm(g4[0]);
        const float f_s = sigm(g4[1]);
        const float g_t = tanh_fast(g4[2]);
        const float o_s = sigm(g4[3]);
        c_state = f_s * c_state + i_s * g_t;
        const float hn = o_s * tanh_fast(c_state);

        // ---- per-wave publish (R13/R14): pack the wave's 64 tagged fp16 in
        //      its PRIVATE LDS scratch (intra-wave lgkm order, no barrier),
        //      then 16 lanes store one contiguous 128B run = 2 full sectors
        //      in ONE wave-instruction (single event/sector) ----
        {
            const unsigned pub_phase = (((unsigned)t >> 1) & 1u) ^ 1u;
            unsigned short hb16 = __builtin_bit_cast(unsigned short, (_Float16)hn);
            hb16 = (unsigned short)((hb16 & 0xFFFEu) | pub_phase);
            unsigned short* ps = (unsigned short*)gw;    // 128B wave staging
            ps[my_row * 8 + (lane & 7)] = hb16;
            if (lane < 16) {
                const u64 pk = *(const u64*)(ps + 4 * lane);
                u64* dst = (u64*)h16 + (size_t)(t & 1) * HBUF_U64
                           + team * 1024 + p * 64 + wv * 16 + lane;
                __hip_atomic_store(dst, pk, __ATOMIC_RELAXED,
                                   __HIP_MEMORY_SCOPE_AGENT);
            }
        }

        if (t == my_tstar)
            out[(rowbase + my_row) * HID + my_unit] = c_state;

        // ---- filler between publish and next poll: x pipeline + x-MFMA(t+1)
        //      then the tuned s_sleep so poll round-0 samples past producer
        //      visibility ----
        if (XA) {
#pragma unroll
            for (int kt = 0; kt < 4; ++kt) xf[kt] = xn[kt];
            const int t2 = (t + 2 <= tmax) ? (t + 2) : tmax;
            const _Float16* xs2 = x_all + ((size_t)t2 * BATCH + rowbase + arow) * DIN;
#pragma unroll
            for (int kt = 0; kt < 4; ++kt)
                xn[kt] = *(const half8*)(xs2 + kt * 32 + kq * 8);
        } else {
#pragma unroll
            for (int kt = 0; kt < 4; ++kt)
                xf[kt] = cvt8(xraw[2 * kt], xraw[2 * kt + 1]);
        }

        a0 = (float4v){bias0, bias0, bias0, bias0}; b0 = (float4v){0,0,0,0};
        c0 = (float4v){0,0,0,0};                    d0 = (float4v){0,0,0,0};
        a1 = (float4v){bias1, bias1, bias1, bias1}; b1 = (float4v){0,0,0,0};
        c1 = (float4v){0,0,0,0};                    d1 = (float4v){0,0,0,0};
        a0 = __builtin_amdgcn_mfma_f32_16x16x32_f16(xf[0], wihf0[0], a0, 0, 0, 0);
        b0 = __builtin_amdgcn_mfma_f32_16x16x32_f16(xf[1], wihf0[1], b0, 0, 0, 0);
        c0 = __builtin_amdgcn_mfma_f32_16x16x32_f16(xf[2], wihf0[2], c0, 0, 0, 0);
        d0 = __builtin_amdgcn_mfma_f32_16x16x32_f16(xf[3], wihf0[3], d0, 0, 0, 0);
        a1 = __builtin_amdgcn_mfma_f32_16x16x32_f16(xf[0], wihf1[0], a1, 0, 0, 0);
        b1 = __builtin_amdgcn_mfma_f32_16x16x32_f16(xf[1], wihf1[1], b1, 0, 0, 0);
        c1 = __builtin_amdgcn_mfma_f32_16x16x32_f16(xf[2], wihf1[2], c1, 0, 0, 0);
        d1 = __builtin_amdgcn_mfma_f32_16x16x32_f16(xf[3], wihf1[3], d1, 0, 0, 0);

        // tuned pre-poll delay: ~384 cyc (bracketed optimal: R6/R3/R12)
        __builtin_amdgcn_s_sleep(6);
    }
}

extern "C" void kernel_launch(void* const* d_in, const int* in_sizes, int n_in,
                              void* d_out, int out_size, void* d_ws, size_t ws_size,
                              hipStream_t stream)
{
    const int*   ids  = (const int*)d_in[0];
    const int*   slen = (const int*)d_in[1];
    const float* emb  = (const float*)d_in[2];
    const float* wih  = (const float*)d_in[3];
    const float* whh  = (const float*)d_in[4];
    const float* bih  = (const float*)d_in[5];
    const float* bhh  = (const float*)d_in[6];
    float* out = (float*)d_out;

    _Float16* h16   = (_Float16*)((char*)d_ws + WS_H16_OFF);
    int*      bar   = (int*)((char*)d_ws + WS_BAR_OFF);
    _Float16* x_all = (_Float16*)((char*)d_ws + WS_XALL_OFF);

    if (ws_size >= WS_NEED) {
        hipMemsetAsync(bar, 0, sizeof(int), stream);
        hipLaunchKernelGGL((lstm_persistent<true>), dim3(256), dim3(256), 0, stream,
                           ids, slen, emb, wih, whh, bih, bhh, out,
                           h16, x_all, bar);
    } else {
        hipLaunchKernelGGL((lstm_persistent<false>), dim3(256), dim3(256), 0, stream,
                           ids, slen, emb, wih, whh, bih, bhh, out,
                           h16, x_all, bar);
    }
}